// Round 9
// baseline (47.886 us; speedup 1.0000x reference)
//
#include <hip/hip_runtime.h>
#include <hip/hip_bf16.h>

typedef __attribute__((ext_vector_type(8)))  short bf16x8;
typedef __attribute__((ext_vector_type(16))) float f32x16;

#define I_N 256
#define T_N 256
#define L_N 32
#define E_N 128
#define P_N 49

// ---- pre-pass: pack text(B) + image(A) into 32x32x16 MFMA fragment order ----
// B frag [t*8+ks][lane][8]: col l = lane&31 (token), k = ks*16 + (lane>>5)*8 + j
// A frag [i*16 + pt*8 + ks][lane][8]: patch = pt*32 + (lane&31), same k map.
__global__ __launch_bounds__(256) void pack_all(const float* __restrict__ txt,
                                                const float* __restrict__ img,
                                                unsigned short* __restrict__ bpre,
                                                unsigned short* __restrict__ apre) {
    const int bid = blockIdx.x;
    if (bid < 512) {                                 // ---- text
        int gid  = bid * 256 + threadIdx.x;
        int lane = gid & 63;
        int ks   = (gid >> 6) & 7;
        int t    = gid >> 9;
        int l    = lane & 31;
        int e0   = ks * 16 + (lane >> 5) * 8;
        const float* src = txt + (t * L_N + l) * E_N + e0;
        union { unsigned short u[8]; bf16x8 v; } o;
        #pragma unroll
        for (int j = 0; j < 8; ++j) {
            __hip_bfloat16 h = __float2bfloat16(src[j]);
            o.u[j] = *reinterpret_cast<unsigned short*>(&h);
        }
        ((bf16x8*)bpre)[gid] = o.v;
    } else {                                         // ---- image
        int gid   = (bid - 512) * 256 + threadIdx.x;
        int lane  = gid & 63;
        int ks    = (gid >> 6) & 7;
        int pt    = (gid >> 9) & 1;
        int i     = gid >> 10;
        int patch = pt * 32 + (lane & 31);
        int e0    = ks * 16 + (lane >> 5) * 8;
        const float* src = img + i * (E_N * P_N) + e0 * P_N + patch;
        union { unsigned short u[8]; bf16x8 v; } o;
        #pragma unroll
        for (int j = 0; j < 8; ++j) {
            float x = (patch < P_N) ? src[j * P_N] : 0.0f;
            __hip_bfloat16 h = __float2bfloat16(x);
            o.u[j] = *reinterpret_cast<unsigned short*>(&h);
        }
        ((bf16x8*)apre)[gid] = o.v;
    }
}

// ---- main kernel: grid 768 = exactly 3 blocks/CU (12 waves/CU, regs ~168). ----
// Tail-free persistent mapping: block b -> text-stride r=b%12, images (b/12)*4+w.
// Wave owns image i (A-frags pinned), grid-strides texts t = r, r+12, ... (21-22).
// 4 waves/block iterate the SAME texts -> B-reads share L1/L2. No LDS, no barriers.
__global__ __launch_bounds__(256, 3) void clip_mfma(
    const unsigned short* __restrict__ apre,
    const unsigned short* __restrict__ bpre,
    const int*   __restrict__ tlen,
    const float* __restrict__ nlt,
    float*       __restrict__ out) {

    const int wid  = threadIdx.x >> 6;
    const int lane = threadIdx.x & 63;
    const int b    = blockIdx.x;           // 0..767
    const int r    = b % 12;               // text stride offset
    const int i    = (b / 12) * 4 + wid;   // image
    const float scale = expf(nlt[0]);
    const bool  lo32  = (lane < 32);

    // Pin image A-frags: 2 patch-tiles x 8 k-steps = 64 regs, reused for ~22 texts.
    bf16x8 af[2][8];
    const bf16x8* ap = (const bf16x8*)apre + (size_t)i * 16 * 64;
    #pragma unroll
    for (int pt = 0; pt < 2; ++pt)
        #pragma unroll
        for (int ks = 0; ks < 8; ++ks)
            af[pt][ks] = ap[(pt * 8 + ks) * 64 + lane];

    const bf16x8* bp = (const bf16x8*)bpre;

    #pragma unroll 1
    for (int t = r; t < T_N; t += 12) {
        // 8 coalesced 16B loads: wave reads 1KB contiguous per frag (L1/L2-hot).
        bf16x8 bf[8];
        const bf16x8* tb = bp + (size_t)t * 8 * 64;
        #pragma unroll
        for (int ks = 0; ks < 8; ++ks)
            bf[ks] = tb[ks * 64 + lane];

        f32x16 a0, a1;
        #pragma unroll
        for (int rr = 0; rr < 16; ++rr) { a0[rr] = 0.0f; a1[rr] = 0.0f; }

        __builtin_amdgcn_s_setprio(1);
        #pragma unroll
        for (int ks = 0; ks < 8; ++ks) {
            a0 = __builtin_amdgcn_mfma_f32_32x32x16_bf16(af[0][ks], bf[ks], a0, 0, 0, 0);
            a1 = __builtin_amdgcn_mfma_f32_32x32x16_bf16(af[1][ks], bf[ks], a1, 0, 0, 0);
        }
        __builtin_amdgcn_s_setprio(0);

        // Reduce: max over 49 patches, sum over 32 tokens.
        // C: col = lane&31 (token), row = (reg&3)+8*(reg>>2)+4*(lane>>5).
        // Tile1 (patches 32..63): regs 0..7 valid both halves; reg 8 lo-half (p=48).
        float m = a0[0];
        #pragma unroll
        for (int rr = 1; rr < 16; ++rr) m = fmaxf(m, a0[rr]);
        #pragma unroll
        for (int rr = 0; rr < 8; ++rr)  m = fmaxf(m, a1[rr]);
        m = fmaxf(m, lo32 ? a1[8] : -INFINITY);
        m = fmaxf(m, __shfl_xor(m, 32));            // merge halves -> 49-patch max
        float s = m;
        #pragma unroll
        for (int off = 1; off <= 16; off <<= 1)
            s += __shfl_xor(s, off);                // sum over 32 token cols

        if (lane == 0) {
            float match = (s / (float)tlen[t]) * scale;
            out[i * T_N + t]             = match;   // logits_per_image [I][T]
            out[I_N * T_N + t * I_N + i] = match;   // logits_per_text  [T][I]
        }
    }
}

extern "C" void kernel_launch(void* const* d_in, const int* in_sizes, int n_in,
                              void* d_out, int out_size, void* d_ws, size_t ws_size,
                              hipStream_t stream) {
    const float* img  = (const float*)d_in[0];
    const float* txt  = (const float*)d_in[1];
    const int*   tlen = (const int*)d_in[2];
    const float* nlt  = (const float*)d_in[3];
    float*       out  = (float*)d_out;

    unsigned short* bpre = (unsigned short*)d_ws;                       // 2 MB
    unsigned short* apre = (unsigned short*)((char*)d_ws + (2u << 20)); // 4 MB

    pack_all<<<1536, 256, 0, stream>>>(txt, img, bpre, apre);

    clip_mfma<<<768, 256, 0, stream>>>(apre, bpre, tlen, nlt, out);
}